// Round 2
// baseline (8351.698 us; speedup 1.0000x reference)
//
#include <hip/hip_runtime.h>
#include <hip/hip_bf16.h>
#include <math.h>

#define BB 2
#define SS 1024
#define DD 768
#define HH 12
#define DHH 64
#define LL 4
#define VV 32000
#define FF 3072
#define MR (BB*SS)   // 2048 rows

// Flag-dependent load: float tensors may be bf16 or f32; detect kernel decides.
// Indexing is in ELEMENTS, so per-layer offsets are dtype-independent.
template<bool BF>
__device__ inline float ldg_t(const void* p, size_t i) {
    if (BF) return __bfloat162float(((const __hip_bfloat16*)p)[i]);
    else    return ((const float*)p)[i];
}

// ---------------- dtype detect: ln1_g is all ones ----------------
__global__ void detect_kernel(const unsigned* __restrict__ ln1g, int* __restrict__ flag) {
    *flag = (ln1g[0] == 0x3F803F80u) ? 1 : 0;   // bf16 ones pair vs f32 one
}

// ---------------- embedding + positional encoding ----------------
template<bool BF>
__device__ void embed_body(const int* tokens, const void* tok_emb, float* x) {
    int row = blockIdx.x;            // b*S + s
    int s = row & (SS - 1);
    int tok = tokens[row];
    const float scale = 27.712812921102035f;   // sqrt(768)
    for (int d = threadIdx.x; d < DD; d += 256) {
        float val = ldg_t<BF>(tok_emb, (size_t)tok * DD + d) * scale;
        int i2 = d & ~1;
        float freq = expf(-9.210340371976184f * (float)i2 / (float)DD);
        float arg = (float)s * freq;
        val += (d & 1) ? cosf(arg) : sinf(arg);
        x[(size_t)row * DD + d] = val;
    }
}
__global__ __launch_bounds__(256) void embed_kernel(
    const int* __restrict__ flag, const int* __restrict__ tokens,
    const void* __restrict__ tok_emb, float* __restrict__ x)
{
    if (*flag) embed_body<true>(tokens, tok_emb, x);
    else       embed_body<false>(tokens, tok_emb, x);
}

// ---------------- layernorm (row of 768); goff/boff are element offsets ----------------
template<bool BF>
__device__ void ln_body(const float* x, const void* g, size_t goff,
                        const void* bta, size_t boff, float* out,
                        float* rs, float* rq) {
    int row = blockIdx.x;
    const float* xr = x + (size_t)row * DD;
    int t = threadIdx.x;
    float v0 = xr[t], v1 = xr[t + 256], v2 = xr[t + 512];
    float s = v0 + v1 + v2;
    float sq = v0 * v0 + v1 * v1 + v2 * v2;
    for (int off = 32; off; off >>= 1) { s += __shfl_xor(s, off); sq += __shfl_xor(sq, off); }
    int wave = t >> 6, lane = t & 63;
    if (lane == 0) { rs[wave] = s; rq[wave] = sq; }
    __syncthreads();
    s = rs[0] + rs[1] + rs[2] + rs[3];
    sq = rq[0] + rq[1] + rq[2] + rq[3];
    float mu = s * (1.0f / DD);
    float var = sq * (1.0f / DD) - mu * mu;
    float rstd = rsqrtf(var + 1e-5f);
    float* orow = out + (size_t)row * DD;
    orow[t]       = (v0 - mu) * rstd * ldg_t<BF>(g, goff + t)       + ldg_t<BF>(bta, boff + t);
    orow[t + 256] = (v1 - mu) * rstd * ldg_t<BF>(g, goff + t + 256) + ldg_t<BF>(bta, boff + t + 256);
    orow[t + 512] = (v2 - mu) * rstd * ldg_t<BF>(g, goff + t + 512) + ldg_t<BF>(bta, boff + t + 512);
}
__global__ __launch_bounds__(256) void ln_kernel(
    const int* __restrict__ flag, const float* __restrict__ x,
    const void* __restrict__ g, size_t goff,
    const void* __restrict__ bta, size_t boff, float* __restrict__ out)
{
    __shared__ float rs[4], rq[4];
    if (*flag) ln_body<true>(x, g, goff, bta, boff, out, rs, rq);
    else       ln_body<false>(x, g, goff, bta, boff, out, rs, rq);
}

// ---------------- tiled GEMM: C = A[M,K](f32) @ W[K,N] + bias, fused epilogue ----------------
// woff/boff: element offsets into W/bias for the current layer.
template<bool BF, bool GELU_ACT, bool RES, bool TOOUT>
__device__ void gemm_body(float (*As)[68], float (*Bs)[64],
                          const float* A, const void* W, size_t woff,
                          const void* bias, size_t boff,
                          const float* res, float* Cf, void* Co,
                          int M, int N, int K)
{
    int tid = threadIdx.x;
    int tx = tid & 15, ty = tid >> 4;
    int bm = blockIdx.y * 64, bn = blockIdx.x * 64;
    float acc[4][4] = {};
    int la_col = tid & 15;
    int la_row = tid >> 4;
    int lb_col = tid & 63;
    int lb_row = tid >> 6;

    for (int k0 = 0; k0 < K; k0 += 16) {
#pragma unroll
        for (int p = 0; p < 4; ++p) {
            int r = la_row + p * 16;
            As[la_col][r] = A[(size_t)(bm + r) * K + k0 + la_col];
        }
#pragma unroll
        for (int p = 0; p < 4; ++p) {
            int r = lb_row + p * 4;
            Bs[r][lb_col] = ldg_t<BF>(W, woff + (size_t)(k0 + r) * N + bn + lb_col);
        }
        __syncthreads();
#pragma unroll
        for (int kk = 0; kk < 16; ++kk) {
            float4 a = *reinterpret_cast<const float4*>(&As[kk][ty * 4]);
            float4 b = *reinterpret_cast<const float4*>(&Bs[kk][tx * 4]);
            float av[4] = {a.x, a.y, a.z, a.w};
            float bv[4] = {b.x, b.y, b.z, b.w};
#pragma unroll
            for (int i = 0; i < 4; ++i)
#pragma unroll
                for (int j = 0; j < 4; ++j)
                    acc[i][j] += av[i] * bv[j];
        }
        __syncthreads();
    }
#pragma unroll
    for (int i = 0; i < 4; ++i) {
        int row = bm + ty * 4 + i;
#pragma unroll
        for (int j = 0; j < 4; ++j) {
            int col = bn + tx * 4 + j;
            float vv = acc[i][j] + ldg_t<BF>(bias, boff + col);
            if (GELU_ACT) vv = 0.5f * vv * (1.0f + erff(vv * 0.7071067811865475f));
            if (RES) vv += res[(size_t)row * N + col];
            if (TOOUT) {
                if (BF) ((__hip_bfloat16*)Co)[(size_t)row * N + col] = __float2bfloat16(vv);
                else    ((float*)Co)[(size_t)row * N + col] = vv;
            } else {
                Cf[(size_t)row * N + col] = vv;
            }
        }
    }
}
template<bool GELU_ACT, bool RES, bool TOOUT>
__global__ __launch_bounds__(256) void gemm_kernel(
    const int* __restrict__ flag, const float* __restrict__ A,
    const void* __restrict__ W, size_t woff,
    const void* __restrict__ bias, size_t boff,
    const float* __restrict__ res, float* __restrict__ Cf, void* __restrict__ Co,
    int M, int N, int K)
{
    __shared__ float As[16][68];
    __shared__ float Bs[16][64];
    if (*flag) gemm_body<true,  GELU_ACT, RES, TOOUT>(As, Bs, A, W, woff, bias, boff, res, Cf, Co, M, N, K);
    else       gemm_body<false, GELU_ACT, RES, TOOUT>(As, Bs, A, W, woff, bias, boff, res, Cf, Co, M, N, K);
}

// ---------------- causal attention, one block per (b,h,q-row); all f32 ws ----------------
__global__ __launch_bounds__(256) void attn_kernel(
    const float* __restrict__ q, const float* __restrict__ k,
    const float* __restrict__ v, float* __restrict__ y)
{
    int qi = blockIdx.x, h = blockIdx.y, b = blockIdx.z;
    int tid = threadIdx.x, wave = tid >> 6, lane = tid & 63;
    __shared__ float sc[SS];
    __shared__ float red[4];
    __shared__ float pv[4][64];
    int headoff = h * DHH;
    size_t rowbase = (size_t)(b * SS + qi) * DD + headoff;
    float ql = q[rowbase + lane];
    int n = qi + 1;

    for (int j = wave; j < n; j += 4) {
        float p = ql * k[(size_t)(b * SS + j) * DD + headoff + lane];
        for (int off = 32; off; off >>= 1) p += __shfl_xor(p, off);
        if (lane == 0) sc[j] = p * 0.125f;
    }
    __syncthreads();

    float m = -1e30f;
    for (int j = tid; j < n; j += 256) m = fmaxf(m, sc[j]);
    for (int off = 32; off; off >>= 1) m = fmaxf(m, __shfl_xor(m, off));
    if (lane == 0) red[wave] = m;
    __syncthreads();
    m = fmaxf(fmaxf(red[0], red[1]), fmaxf(red[2], red[3]));
    __syncthreads();

    float ssum = 0.f;
    for (int j = tid; j < n; j += 256) { float e = expf(sc[j] - m); sc[j] = e; ssum += e; }
    for (int off = 32; off; off >>= 1) ssum += __shfl_xor(ssum, off);
    if (lane == 0) red[wave] = ssum;
    __syncthreads();
    float inv = 1.0f / (red[0] + red[1] + red[2] + red[3]);

    float acc = 0.f;
    for (int j = wave; j < n; j += 4) acc += sc[j] * v[(size_t)(b * SS + j) * DD + headoff + lane];
    pv[wave][lane] = acc;
    __syncthreads();
    if (tid < 64)
        y[(size_t)(b * SS + qi) * DD + headoff + tid] =
            (pv[0][tid] + pv[1][tid] + pv[2][tid] + pv[3][tid]) * inv;
}

extern "C" void kernel_launch(void* const* d_in, const int* in_sizes, int n_in,
                              void* d_out, int out_size, void* d_ws, size_t ws_size,
                              hipStream_t stream)
{
    const int* tokens = (const int*)d_in[0];
    const void* tok_emb = d_in[1];
    const void *Wq = d_in[2], *bq = d_in[3], *Wk = d_in[4], *bk = d_in[5];
    const void *Wv = d_in[6], *bv = d_in[7], *Wo = d_in[8], *bo = d_in[9];
    const void *ln1_g = d_in[10], *ln1_b = d_in[11], *ln2_g = d_in[12], *ln2_b = d_in[13];
    const void *W1 = d_in[14], *b1 = d_in[15], *W2 = d_in[16], *b2 = d_in[17];
    const void *lnf_g = d_in[18], *lnf_b = d_in[19], *fc_W = d_in[20], *fc_b = d_in[21];

    // d_ws layout: [flag 256B][x MR*DD f32][hbuf MR*DD f32][big MR*FF f32]
    // q/k/v live in `big`; ffb aliases it after attention (they never coexist).
    int* flag   = (int*)d_ws;
    float* x    = (float*)((char*)d_ws + 256);
    float* hbuf = x + (size_t)MR * DD;
    float* big  = hbuf + (size_t)MR * DD;
    float* qb = big;
    float* kb = big + (size_t)MR * DD;
    float* vb = big + 2 * (size_t)MR * DD;
    float* ffb = big;   // [2048,3072]

    dim3 blk(256);
    dim3 gD(DD / 64, MR / 64);
    dim3 gF(FF / 64, MR / 64);
    dim3 gV(VV / 64, MR / 64);

    detect_kernel<<<1, 1, 0, stream>>>((const unsigned*)ln1_g, flag);
    embed_kernel<<<MR, blk, 0, stream>>>(flag, tokens, tok_emb, x);

    for (int l = 0; l < LL; ++l) {
        size_t oW  = (size_t)l * DD * DD, oB  = (size_t)l * DD;
        size_t oW1 = (size_t)l * DD * FF, oB1 = (size_t)l * FF;
        size_t oW2 = (size_t)l * FF * DD;

        ln_kernel<<<MR, blk, 0, stream>>>(flag, x, ln1_g, oB, ln1_b, oB, hbuf);
        gemm_kernel<false, false, false><<<gD, blk, 0, stream>>>(
            flag, hbuf, Wq, oW, bq, oB, nullptr, qb, nullptr, MR, DD, DD);
        gemm_kernel<false, false, false><<<gD, blk, 0, stream>>>(
            flag, hbuf, Wk, oW, bk, oB, nullptr, kb, nullptr, MR, DD, DD);
        gemm_kernel<false, false, false><<<gD, blk, 0, stream>>>(
            flag, hbuf, Wv, oW, bv, oB, nullptr, vb, nullptr, MR, DD, DD);
        attn_kernel<<<dim3(SS, HH, BB), blk, 0, stream>>>(qb, kb, vb, hbuf);
        gemm_kernel<false, true, false><<<gD, blk, 0, stream>>>(
            flag, hbuf, Wo, oW, bo, oB, x, x, nullptr, MR, DD, DD);
        ln_kernel<<<MR, blk, 0, stream>>>(flag, x, ln2_g, oB, ln2_b, oB, hbuf);
        gemm_kernel<true, false, false><<<gF, blk, 0, stream>>>(
            flag, hbuf, W1, oW1, b1, oB1, nullptr, ffb, nullptr, MR, FF, DD);
        gemm_kernel<false, true, false><<<gD, blk, 0, stream>>>(
            flag, ffb, W2, oW2, b2, oB, x, x, nullptr, MR, DD, FF);
    }

    ln_kernel<<<MR, blk, 0, stream>>>(flag, x, lnf_g, 0, lnf_b, 0, hbuf);
    gemm_kernel<false, false, true><<<gV, blk, 0, stream>>>(
        flag, hbuf, fc_W, 0, fc_b, 0, nullptr, nullptr, d_out, MR, VV, DD);
}